// Round 6
// baseline (104.221 us; speedup 1.0000x reference)
//
#include <hip/hip_runtime.h>

typedef __attribute__((ext_vector_type(8))) __bf16 bf16x8;
typedef __attribute__((ext_vector_type(8))) unsigned short ushort8;
typedef __attribute__((ext_vector_type(4))) float floatx4;
typedef __attribute__((ext_vector_type(16))) float floatx16;

__device__ __forceinline__ unsigned short f2bf(float f) {
    unsigned int u = __builtin_bit_cast(unsigned int, f);
    unsigned int r = u + 0x7FFFu + ((u >> 16) & 1u);
    return (unsigned short)(r >> 16);
}
__device__ __forceinline__ float bf2f(unsigned short h) {
    return __builtin_bit_cast(float, ((unsigned int)h) << 16);
}

// Prep: build augmented codebook wext[512][80] bf16:
//   cols 0..63 = -2*w, col 64 = bf16(||w||^2), col 65 = bf16(residual), 66..79 = 0.
// Score = <A_ext[code], [x|1|1|0..]> = ||w||^2 - 2<w,x>  (computed entirely by MFMA).
__global__ void vq_prep(const float* __restrict__ w, unsigned short* __restrict__ wext) {
    const int t = threadIdx.x;
    const int row = blockIdx.x * 4 + (t >> 6);
    const int c = t & 63;
    float v = w[row * 64 + c];
    wext[row * 80 + c] = f2bf(-2.f * v);
    float s = v * v;
#pragma unroll
    for (int off = 32; off; off >>= 1) s += __shfl_xor(s, off, 64);
    if (c == 0) {
        const unsigned short hi = f2bf(s);
        wext[row * 80 + 64] = hi;
        wext[row * 80 + 65] = f2bf(s - bf2f(hi));
    }
    if (c >= 2 && c < 16) wext[row * 80 + 64 + c] = 0;  // cols 66..79
}

// 1024 blocks x 256 thr (4 waves). Wave wv holds codes [wv*128, wv*128+128) as
// stationary A-fragments in VGPRs. 4 X-tiles per block, double-buffered LDS.
__global__ void __launch_bounds__(256) vq_main(
    const float* __restrict__ in,             // [32][64][4096]
    const float* __restrict__ w,              // [512][64] fp32 (epilogue gather)
    const unsigned short* __restrict__ wext,  // [512][80] augmented bf16
    float* __restrict__ out,                  // [32][64][4096]
    float* __restrict__ partials) {           // [1024] per-block loss sums
    __shared__ unsigned short xs[2][2048];    // [g=k>>3][pos][e=k&7] bf16, 4KB each
    __shared__ float red[4][32];
    __shared__ float ws4[4];

    const int t = threadIdx.x;
    const int lane = t & 63;
    const int wv = t >> 6;
    const int bid = blockIdx.x;
    const int col = lane & 31;
    const int hi = lane >> 5;

    // ---- stationary A-fragments: 4 code-tiles x 5 k-chunks (80 VGPR) ----
    bf16x8 A[4][5];
#pragma unroll
    for (int i = 0; i < 4; ++i) {
        const int row = (wv * 4 + i) * 32 + col;
#pragma unroll
        for (int ch = 0; ch < 5; ++ch)
            A[i][ch] = *(const bf16x8*)&wext[row * 80 + ch * 16 + hi * 8];
    }
    // constant B-fragment for the augmentation chunk (k=64..79): [1,1,0,...]
    ushort8 b4u = {0, 0, 0, 0, 0, 0, 0, 0};
    if (hi == 0) { b4u[0] = 0x3F80; b4u[1] = 0x3F80; }
    const bf16x8 Bf4 = __builtin_bit_cast(bf16x8, b4u);

    float x2acc = 0.f;
    float smin_acc = 0.f;

    // ---- stage tile 0 ----
    {
        const int gt = bid * 4;
        const float* in_base = in + ((size_t)(gt >> 7) * 64) * 4096 + ((gt & 127) << 5);
#pragma unroll
        for (int it = 0; it < 2; ++it) {
            const int task = t + 256 * it;
            const int c = task >> 3, q = task & 7, p0 = q * 4;
            floatx4 v = *(const floatx4*)(in_base + (size_t)c * 4096 + p0);
            x2acc += v[0] * v[0] + v[1] * v[1] + v[2] * v[2] + v[3] * v[3];
            unsigned short* p = &xs[0][((c >> 3) * 32 + p0) * 8 + (c & 7)];
            p[0] = f2bf(v[0]); p[8] = f2bf(v[1]); p[16] = f2bf(v[2]); p[24] = f2bf(v[3]);
        }
    }
    __syncthreads();

#pragma unroll
    for (int ti = 0; ti < 4; ++ti) {
        const int cur = ti & 1;
        const int gt = bid * 4 + ti;

        // B-fragments for this tile
        bf16x8 Bf[4];
#pragma unroll
        for (int ch = 0; ch < 4; ++ch)
            Bf[ch] = *(const bf16x8*)&xs[cur][((2 * ch + hi) * 32 + col) * 8];

        // stage next tile into the other buffer (loads fly under compute)
        if (ti < 3) {
            const int gn = gt + 1;
            const float* in_base = in + ((size_t)(gn >> 7) * 64) * 4096 + ((gn & 127) << 5);
#pragma unroll
            for (int it = 0; it < 2; ++it) {
                const int task = t + 256 * it;
                const int c = task >> 3, q = task & 7, p0 = q * 4;
                floatx4 v = *(const floatx4*)(in_base + (size_t)c * 4096 + p0);
                x2acc += v[0] * v[0] + v[1] * v[1] + v[2] * v[2] + v[3] * v[3];
                unsigned short* p = &xs[cur ^ 1][((c >> 3) * 32 + p0) * 8 + (c & 7)];
                p[0] = f2bf(v[0]); p[8] = f2bf(v[1]); p[16] = f2bf(v[2]); p[24] = f2bf(v[3]);
            }
        }

        // ---- scores for this wave's 128 codes ----
        float best = 1e30f;
#pragma unroll
        for (int i = 0; i < 4; ++i) {
            floatx16 acc = {0.f, 0.f, 0.f, 0.f, 0.f, 0.f, 0.f, 0.f,
                            0.f, 0.f, 0.f, 0.f, 0.f, 0.f, 0.f, 0.f};
            acc = __builtin_amdgcn_mfma_f32_32x32x16_bf16(A[i][0], Bf[0], acc, 0, 0, 0);
            acc = __builtin_amdgcn_mfma_f32_32x32x16_bf16(A[i][1], Bf[1], acc, 0, 0, 0);
            acc = __builtin_amdgcn_mfma_f32_32x32x16_bf16(A[i][2], Bf[2], acc, 0, 0, 0);
            acc = __builtin_amdgcn_mfma_f32_32x32x16_bf16(A[i][3], Bf[3], acc, 0, 0, 0);
            acc = __builtin_amdgcn_mfma_f32_32x32x16_bf16(A[i][4], Bf4,   acc, 0, 0, 0);
            const int code_base = (wv * 4 + i) * 32;
            float pk[16];
#pragma unroll
            for (int q = 0; q < 4; ++q) {
#pragma unroll
                for (int rr = 0; rr < 4; ++rr) {
                    const int r = q * 4 + rr;
                    const unsigned int code = (unsigned int)(code_base + 8 * q + 4 * hi + rr);
                    pk[r] = __builtin_bit_cast(float,
                        (__builtin_bit_cast(unsigned int, acc[r]) & 0xFFFFFE00u) | code);
                }
            }
            // depth-4 tree min of 16, then fold into best
#pragma unroll
            for (int s2 = 8; s2 >= 1; s2 >>= 1)
#pragma unroll
                for (int r = 0; r < s2; ++r) pk[r] = fminf(pk[r], pk[r + s2]);
            best = fminf(best, pk[0]);
        }
        best = fminf(best, __shfl_xor(best, 32, 64));
        if (lane < 32) red[wv][col] = best;
        __syncthreads();

        // all waves: final min over the 4 wave-partials (per position)
        const float v = fminf(fminf(red[0][col], red[1][col]),
                              fminf(red[2][col], red[3][col]));
        if (wv == 0 && lane < 32)
            smin_acc += __builtin_bit_cast(float,
                __builtin_bit_cast(unsigned int, v) & 0xFFFFFE00u);

        // epilogue: gather fp32 code rows -> out
        float* out_base = out + ((size_t)(gt >> 7) * 64) * 4096 + ((gt & 127) << 5);
#pragma unroll
        for (int it = 0; it < 2; ++it) {
            const int task = t + 256 * it;
            const int c = task >> 3, q = task & 7, p0 = q * 4;
            floatx4 qv;
#pragma unroll
            for (int r = 0; r < 4; ++r) {
                const float pk = __shfl(v, p0 + r, 64);
                const int idx = (int)(__builtin_bit_cast(unsigned int, pk) & 511u);
                qv[r] = w[idx * 64 + c];
            }
            *(floatx4*)(out_base + (size_t)c * 4096 + p0) = qv;
        }
        __syncthreads();  // red free for next tile; next buffer fully staged
    }

    // ---- loss partial ----
    float tot = x2acc + ((wv == 0 && lane < 32) ? smin_acc : 0.f);
#pragma unroll
    for (int off = 1; off < 64; off <<= 1) tot += __shfl_xor(tot, off, 64);
    if (lane == 0) ws4[wv] = tot;
    __syncthreads();
    if (t == 0) partials[bid] = ws4[0] + ws4[1] + ws4[2] + ws4[3];
}

// Final: sum 1024 per-block partials -> scalar loss.
__global__ void vq_reduce(const float* __restrict__ partials, float* __restrict__ loss) {
    const int t = threadIdx.x;
    float s = partials[t] + partials[t + 256] + partials[t + 512] + partials[t + 768];
#pragma unroll
    for (int off = 32; off; off >>= 1) s += __shfl_xor(s, off, 64);
    __shared__ float ws4[4];
    if ((t & 63) == 0) ws4[t >> 6] = s;
    __syncthreads();
    if (t == 0) loss[0] = (ws4[0] + ws4[1] + ws4[2] + ws4[3]) * (1.25f / 8388608.f);
}

extern "C" void kernel_launch(void* const* d_in, const int* in_sizes, int n_in,
                              void* d_out, int out_size, void* d_ws, size_t ws_size,
                              hipStream_t stream) {
    const float* in = (const float*)d_in[0];
    const float* w  = (const float*)d_in[1];
    float* out = (float*)d_out;
    float* loss = out + 8388608;  // second output (scalar), concatenated
    unsigned short* wext = (unsigned short*)d_ws;                    // 80 KB augmented codebook
    float* partials = (float*)((char*)d_ws + 512 * 80 * 2);          // 4 KB per-block sums

    vq_prep<<<128, 256, 0, stream>>>(w, wext);
    vq_main<<<1024, 256, 0, stream>>>(in, w, wext, out, partials);
    vq_reduce<<<1, 256, 0, stream>>>(partials, loss);
}